// Round 5
// baseline (811.758 us; speedup 1.0000x reference)
//
#include <hip/hip_runtime.h>
#include <math.h>

#define EPSV 1e-8f

constexpr int NSUB = 8;          // sub-bins per row (contention spreading)
constexpr int ROWS_PER_TILE = 1024;

// ---------------------------------------------------------------------------
// K1: per-edge count histogram into sub-binned column-major counters.
// bin(row, s) = s*N + row ; s derived from edge id (same formula in fill).
// ---------------------------------------------------------------------------
__global__ void count_pos_kernel(const int* __restrict__ cu,
                                 const int* __restrict__ ci,
                                 int* __restrict__ cnt,      // [NSUB*N], zeroed
                                 int* __restrict__ pos_u,    // [E]
                                 int* __restrict__ pos_i,    // [E]
                                 int NU, int N, int E) {
    int e = blockIdx.x * blockDim.x + threadIdx.x;
    if (e >= E) return;
    int su = e & 7;
    int si = (e >> 3) & 7;
    int pu = atomicAdd(&cnt[su * N + cu[e]], 1);
    int pi = atomicAdd(&cnt[si * N + (NU + ci[e])], 1);
    __builtin_nontemporal_store(pu, pos_u + e);
    __builtin_nontemporal_store(pi, pos_i + e);
}

// ---------------------------------------------------------------------------
// Scan phase: exclusive scan over logical bins (row-major (row,s) order) of
// the column-major cnt array. Tile = 1024 rows = 8192 logical bins.
// ---------------------------------------------------------------------------
__device__ inline int wave_incl_scan(int v, int lane) {
    #pragma unroll
    for (int off = 1; off < 64; off <<= 1) {
        int t = __shfl_up(v, off, 64);
        if (lane >= off) v += t;
    }
    return v;
}

__global__ void tile_sum_kernel(const int* __restrict__ cnt,
                                int* __restrict__ tsum, int N) {
    __shared__ int ws[16];
    int t = threadIdx.x;
    int r = blockIdx.x * ROWS_PER_TILE + t;
    int s = 0;
    if (r < N) {
        #pragma unroll
        for (int p = 0; p < NSUB; ++p) s += cnt[p * N + r];   // coalesced per plane
    }
    #pragma unroll
    for (int off = 1; off < 64; off <<= 1) s += __shfl_xor(s, off, 64);
    int lane = t & 63, wid = t >> 6;
    if (lane == 0) ws[wid] = s;
    __syncthreads();
    if (t < 16) {
        int x = ws[t];
        #pragma unroll
        for (int off = 1; off < 16; off <<= 1) x += __shfl_xor(x, off, 64);
        if (t == 0) tsum[blockIdx.x] = x;
    }
}

// single block scans tile totals in place -> exclusive offsets (NT <= 256)
__global__ void scan_tsum_kernel(int* __restrict__ tsum, int NT) {
    __shared__ int ws[4];
    int t = threadIdx.x;                 // 256 threads
    int v = (t < NT) ? tsum[t] : 0;
    int lane = t & 63, wid = t >> 6;
    int incl = wave_incl_scan(v, lane);
    if (lane == 63) ws[wid] = incl;
    __syncthreads();
    if (t < 4) {
        int x = ws[t];
        #pragma unroll
        for (int off = 1; off < 4; off <<= 1) {
            int u = __shfl_up(x, off, 64);
            if (t >= off) x += u;
        }
        ws[t] = x;
    }
    __syncthreads();
    int wexcl = (wid == 0) ? 0 : ws[wid - 1];
    if (t < NT) tsum[t] = wexcl + incl - v;
}

__global__ void scan_tile_kernel(const int* __restrict__ cnt,
                                 const int* __restrict__ tsum,
                                 int* __restrict__ rs,       // [N*NSUB] row-major
                                 int N) {
    __shared__ int ws[16];
    int t = threadIdx.x;
    int r = blockIdx.x * ROWS_PER_TILE + t;
    int v[NSUB];
    int tot = 0;
    #pragma unroll
    for (int p = 0; p < NSUB; ++p) {
        int x = (r < N) ? cnt[p * N + r] : 0;
        v[p] = x;
        tot += x;
    }
    int lane = t & 63, wid = t >> 6;
    int incl = wave_incl_scan(tot, lane);
    if (lane == 63) ws[wid] = incl;
    __syncthreads();
    if (t < 16) {
        int x = ws[t];
        #pragma unroll
        for (int off = 1; off < 16; off <<= 1) {
            int u = __shfl_up(x, off, 64);
            if (t >= off) x += u;
        }
        ws[t] = x;
    }
    __syncthreads();
    if (r < N) {
        int wexcl = (wid == 0) ? 0 : ws[wid - 1];
        int run = tsum[blockIdx.x] + wexcl + (incl - tot);
        int out[NSUB];
        #pragma unroll
        for (int p = 0; p < NSUB; ++p) { out[p] = run; run += v[p]; }
        int4* dst = (int4*)(rs + (size_t)r * NSUB);
        dst[0] = make_int4(out[0], out[1], out[2], out[3]);
        dst[1] = make_int4(out[4], out[5], out[6], out[7]);
    }
}

// dense per-row start pointers (drops cnt/rs indirection from hot kernels)
__global__ void row_start_kernel(const int* __restrict__ rs,
                                 int* __restrict__ row_start,
                                 int N, int total_entries) {
    int r = blockIdx.x * blockDim.x + threadIdx.x;
    if (r > N) return;
    row_start[r] = (r == N) ? total_entries : rs[(size_t)r * NSUB];
}

// ---------------------------------------------------------------------------
// K3: fill unified adjacency (global neighbor id, raw softplus weight).
// No atomics: slot = rs[row*8 + s] + pos.
// ---------------------------------------------------------------------------
__global__ void fill_kernel(const float* __restrict__ logit,
                            const int* __restrict__ cu,
                            const int* __restrict__ ci,
                            const int* __restrict__ rs,
                            const int* __restrict__ pos_u,
                            const int* __restrict__ pos_i,
                            int2* __restrict__ adj,
                            int NU, int E) {
    int e = blockIdx.x * blockDim.x + threadIdx.x;
    if (e >= E) return;
    float x = logit[e];
    float w = fmaxf(x, 0.f) + log1pf(expf(-fabsf(x))) + EPSV;  // stable softplus
    int wb = __float_as_int(w);
    int su = e & 7;
    int si = (e >> 3) & 7;
    int u = cu[e];
    int gi = NU + ci[e];
    adj[rs[(size_t)u * NSUB + su]  + pos_u[e]] = make_int2(gi, wb);
    adj[rs[(size_t)gi * NSUB + si] + pos_i[e]] = make_int2(u,  wb);
}

// ---------------------------------------------------------------------------
// K4: per-row degree -> rsqrt(deg+eps). Wave per row, coalesced entry reads.
// ---------------------------------------------------------------------------
__global__ void deg_kernel(const int2* __restrict__ adj,
                           const int* __restrict__ row_start,
                           float* __restrict__ rsq, int N) {
    int row  = blockIdx.x * (blockDim.x >> 6) + (threadIdx.x >> 6);
    int lane = threadIdx.x & 63;
    if (row >= N) return;
    int b = row_start[row], end = row_start[row + 1];
    float s = 0.f;
    for (int j = b + lane; j < end; j += 64) s += __int_as_float(adj[j].y);
    #pragma unroll
    for (int off = 1; off < 64; off <<= 1) s += __shfl_xor(s, off, 64);
    if (lane == 0) rsq[row] = rsqrtf(s + EPSV);
}

// ---------------------------------------------------------------------------
// K5: scale adjacency values to final norm = w * rsq[row] * rsq[nbr]
// ---------------------------------------------------------------------------
__global__ void scale_kernel(int2* __restrict__ adj,
                             const int* __restrict__ row_start,
                             const float* __restrict__ rsq, int N) {
    int row  = blockIdx.x * (blockDim.x >> 6) + (threadIdx.x >> 6);
    int lane = threadIdx.x & 63;
    if (row >= N) return;
    float rr = rsq[row];
    int b = row_start[row], end = row_start[row + 1];
    for (int j = b + lane; j < end; j += 64) {
        int2 v = adj[j];
        v.y = __float_as_int(__int_as_float(v.y) * rr * rsq[v.x]);
        adj[j] = v;
    }
}

// ---------------------------------------------------------------------------
// K6: init fused feature buffer F0 (= w + delta) and output accumulator
// ---------------------------------------------------------------------------
__global__ void init_kernel(const float* __restrict__ user_w, const float* __restrict__ user_d,
                            const float* __restrict__ item_w, const float* __restrict__ item_d,
                            float* __restrict__ F0, float* __restrict__ out,
                            int nu64, int total) {
    int idx = blockIdx.x * blockDim.x + threadIdx.x;
    if (idx >= total) return;
    float v;
    if (idx < nu64) {
        v = user_w[idx] + user_d[idx];
    } else {
        int j = idx - nu64;
        v = item_w[j] + item_d[j];
    }
    F0[idx] = v;                                   // gather source: keep cacheable
    __builtin_nontemporal_store(v, out + idx);     // streaming accumulator
}

// ---------------------------------------------------------------------------
// K7: fused gather SpMM over all rows. One wave per row, lane = feature dim.
// Nontemporal dst/acc stores keep the gather source resident in L2.
// ---------------------------------------------------------------------------
__global__ void __launch_bounds__(256)
gather_kernel(const int2* __restrict__ adj,
              const int* __restrict__ row_start,
              const float* __restrict__ src,
              float* __restrict__ dst,
              float* __restrict__ acc,
              int N, int is_final) {
    int row  = blockIdx.x * (blockDim.x >> 6) + (threadIdx.x >> 6);
    int lane = threadIdx.x & 63;
    if (row >= N) return;

    int k   = row_start[row];
    int end = row_start[row + 1];
    float a = 0.f;

    for (; k + 7 < end; k += 8) {
        int2 p0 = adj[k];     int2 p1 = adj[k + 1];
        int2 p2 = adj[k + 2]; int2 p3 = adj[k + 3];
        int2 p4 = adj[k + 4]; int2 p5 = adj[k + 5];
        int2 p6 = adj[k + 6]; int2 p7 = adj[k + 7];
        float s0 = src[(size_t)p0.x * 64 + lane];
        float s1 = src[(size_t)p1.x * 64 + lane];
        float s2 = src[(size_t)p2.x * 64 + lane];
        float s3 = src[(size_t)p3.x * 64 + lane];
        float s4 = src[(size_t)p4.x * 64 + lane];
        float s5 = src[(size_t)p5.x * 64 + lane];
        float s6 = src[(size_t)p6.x * 64 + lane];
        float s7 = src[(size_t)p7.x * 64 + lane];
        a += __int_as_float(p0.y) * s0;
        a += __int_as_float(p1.y) * s1;
        a += __int_as_float(p2.y) * s2;
        a += __int_as_float(p3.y) * s3;
        a += __int_as_float(p4.y) * s4;
        a += __int_as_float(p5.y) * s5;
        a += __int_as_float(p6.y) * s6;
        a += __int_as_float(p7.y) * s7;
    }
    for (; k + 3 < end; k += 4) {
        int2 p0 = adj[k];     int2 p1 = adj[k + 1];
        int2 p2 = adj[k + 2]; int2 p3 = adj[k + 3];
        float s0 = src[(size_t)p0.x * 64 + lane];
        float s1 = src[(size_t)p1.x * 64 + lane];
        float s2 = src[(size_t)p2.x * 64 + lane];
        float s3 = src[(size_t)p3.x * 64 + lane];
        a += __int_as_float(p0.y) * s0;
        a += __int_as_float(p1.y) * s1;
        a += __int_as_float(p2.y) * s2;
        a += __int_as_float(p3.y) * s3;
    }
    for (; k < end; ++k) {
        int2 p = adj[k];
        a += __int_as_float(p.y) * src[(size_t)p.x * 64 + lane];
    }

    size_t o = (size_t)row * 64 + lane;
    if (is_final) {
        float r = acc[o];
        __builtin_nontemporal_store((r + a) * 0.25f, acc + o);  // 1/(L+1)
    } else {
        dst[o] = a;                 // next layer's gather source: cacheable
        float r = acc[o];
        __builtin_nontemporal_store(r + a, acc + o);
    }
}

// ---------------------------------------------------------------------------
extern "C" void kernel_launch(void* const* d_in, const int* in_sizes, int n_in,
                              void* d_out, int out_size, void* d_ws, size_t ws_size,
                              hipStream_t stream) {
    const float* user_w = (const float*)d_in[0];
    const float* item_w = (const float*)d_in[1];
    const float* user_d = (const float*)d_in[2];
    const float* item_d = (const float*)d_in[3];
    const float* logit  = (const float*)d_in[4];
    const int*   cu     = (const int*)d_in[5];
    const int*   ci     = (const int*)d_in[6];

    const int NU = in_sizes[0] / 64;
    const int NI = in_sizes[1] / 64;
    const int E  = in_sizes[4];
    const int N  = NU + NI;                                  // unified rows
    const int NT = (N + ROWS_PER_TILE - 1) / ROWS_PER_TILE;  // 147 <= 256

    // ---- workspace carve-up (256 B aligned); cnt FIRST (single memset) ----
    char* ws = (char*)d_ws;
    size_t off = 0;
    auto carve = [&](size_t bytes) -> void* {
        void* p = ws + off;
        off = (off + bytes + 255) & ~(size_t)255;
        return p;
    };
    int*   cnt   = (int*)carve((size_t)NSUB * N * 4);   // zeroed each call
    size_t zero_bytes = off;
    int*   rs    = (int*)carve((size_t)NSUB * N * 4);
    int*   rstart= (int*)carve((size_t)(N + 1) * 4);
    float* rsq   = (float*)carve((size_t)N * 4);
    int*   tsum  = (int*)carve((size_t)256 * 4);
    int*   pos_u = (int*)carve((size_t)E * 4);
    int*   pos_i = (int*)carve((size_t)E * 4);
    int2*  adj   = (int2*)carve((size_t)2 * E * 8);
    float* F0    = (float*)carve((size_t)N * 64 * 4);
    float* F1    = (float*)carve((size_t)N * 64 * 4);
    (void)ws_size;

    float* out = (float*)d_out;

    hipMemsetAsync(cnt, 0, zero_bytes, stream);

    // ---- build phase ----
    {
        int eblocks = (E + 255) / 256;
        count_pos_kernel<<<eblocks, 256, 0, stream>>>(cu, ci, cnt, pos_u, pos_i,
                                                      NU, N, E);
        tile_sum_kernel<<<NT, ROWS_PER_TILE, 0, stream>>>(cnt, tsum, N);
        scan_tsum_kernel<<<1, 256, 0, stream>>>(tsum, NT);
        scan_tile_kernel<<<NT, ROWS_PER_TILE, 0, stream>>>(cnt, tsum, rs, N);
        row_start_kernel<<<(N + 256) / 256, 256, 0, stream>>>(rs, rstart, N, 2 * E);
        fill_kernel<<<eblocks, 256, 0, stream>>>(logit, cu, ci, rs, pos_u, pos_i,
                                                 adj, NU, E);
        int rblocks = (N + 3) / 4;
        deg_kernel<<<rblocks, 256, 0, stream>>>(adj, rstart, rsq, N);
        scale_kernel<<<rblocks, 256, 0, stream>>>(adj, rstart, rsq, N);
    }

    // ---- init features + accumulator ----
    {
        int total = N * 64;
        init_kernel<<<(total + 255) / 256, 256, 0, stream>>>(user_w, user_d,
                                                             item_w, item_d,
                                                             F0, out, NU * 64, total);
    }

    // ---- 3 propagation layers, both directions fused per launch ----
    float* Fc = F0; float* Fn = F1;
    const int NUM_LAYERS = 3;
    int rblocks = (N + 3) / 4;
    for (int l = 0; l < NUM_LAYERS; ++l) {
        int fin = (l == NUM_LAYERS - 1) ? 1 : 0;
        gather_kernel<<<rblocks, 256, 0, stream>>>(adj, rstart, Fc, Fn, out, N, fin);
        float* t = Fc; Fc = Fn; Fn = t;
    }
}

// Round 7
// 744.709 us; speedup vs baseline: 1.0900x; 1.0900x over previous
//
#include <hip/hip_runtime.h>
#include <math.h>

#define EPSV 1e-8f

constexpr int NSUB = 8;          // histogram sub-bins per row
constexpr int ROWS_PER_TILE = 1024;

// ---- bf16 helpers (RNE) ----
__device__ inline unsigned short f2bf(float x) {
    unsigned u = __float_as_uint(x);
    unsigned r = u + 0x7FFFu + ((u >> 16) & 1u);
    return (unsigned short)(r >> 16);
}
__device__ inline float bf2f(unsigned short b) {
    return __uint_as_float(((unsigned)b) << 16);
}

// ---------------------------------------------------------------------------
// K1: per-edge count histogram into sub-binned column-major counters.
// ---------------------------------------------------------------------------
__global__ void count_pos_kernel(const int* __restrict__ cu,
                                 const int* __restrict__ ci,
                                 int* __restrict__ cnt,      // [NSUB*N], zeroed
                                 int* __restrict__ pos_u,    // [E]
                                 int* __restrict__ pos_i,    // [E]
                                 int NU, int N, int E) {
    int e = blockIdx.x * blockDim.x + threadIdx.x;
    if (e >= E) return;
    int su = e & 7;
    int si = (e >> 3) & 7;
    pos_u[e] = atomicAdd(&cnt[su * N + cu[e]], 1);
    pos_i[e] = atomicAdd(&cnt[si * N + (NU + ci[e])], 1);
}

// ---------------------------------------------------------------------------
// Scan phase: exclusive scan over logical (row, sub) bins.
// ---------------------------------------------------------------------------
__device__ inline int wave_incl_scan(int v, int lane) {
    #pragma unroll
    for (int off = 1; off < 64; off <<= 1) {
        int t = __shfl_up(v, off, 64);
        if (lane >= off) v += t;
    }
    return v;
}

__global__ void tile_sum_kernel(const int* __restrict__ cnt,
                                int* __restrict__ tsum, int N) {
    __shared__ int ws[16];
    int t = threadIdx.x;
    int r = blockIdx.x * ROWS_PER_TILE + t;
    int s = 0;
    if (r < N) {
        #pragma unroll
        for (int p = 0; p < NSUB; ++p) s += cnt[p * N + r];
    }
    #pragma unroll
    for (int off = 1; off < 64; off <<= 1) s += __shfl_xor(s, off, 64);
    int lane = t & 63, wid = t >> 6;
    if (lane == 0) ws[wid] = s;
    __syncthreads();
    if (t < 16) {
        int x = ws[t];
        #pragma unroll
        for (int off = 1; off < 16; off <<= 1) x += __shfl_xor(x, off, 64);
        if (t == 0) tsum[blockIdx.x] = x;
    }
}

__global__ void scan_tsum_kernel(int* __restrict__ tsum, int NT) {
    __shared__ int ws[4];
    int t = threadIdx.x;                 // 256 threads
    int v = (t < NT) ? tsum[t] : 0;
    int lane = t & 63, wid = t >> 6;
    int incl = wave_incl_scan(v, lane);
    if (lane == 63) ws[wid] = incl;
    __syncthreads();
    if (t < 4) {
        int x = ws[t];
        #pragma unroll
        for (int off = 1; off < 4; off <<= 1) {
            int u = __shfl_up(x, off, 64);
            if (t >= off) x += u;
        }
        ws[t] = x;
    }
    __syncthreads();
    int wexcl = (wid == 0) ? 0 : ws[wid - 1];
    if (t < NT) tsum[t] = wexcl + incl - v;
}

__global__ void scan_tile_kernel(const int* __restrict__ cnt,
                                 const int* __restrict__ tsum,
                                 int* __restrict__ rs,       // [N*NSUB] row-major
                                 int N) {
    __shared__ int ws[16];
    int t = threadIdx.x;
    int r = blockIdx.x * ROWS_PER_TILE + t;
    int v[NSUB];
    int tot = 0;
    #pragma unroll
    for (int p = 0; p < NSUB; ++p) {
        int x = (r < N) ? cnt[p * N + r] : 0;
        v[p] = x;
        tot += x;
    }
    int lane = t & 63, wid = t >> 6;
    int incl = wave_incl_scan(tot, lane);
    if (lane == 63) ws[wid] = incl;
    __syncthreads();
    if (t < 16) {
        int x = ws[t];
        #pragma unroll
        for (int off = 1; off < 16; off <<= 1) {
            int u = __shfl_up(x, off, 64);
            if (t >= off) x += u;
        }
        ws[t] = x;
    }
    __syncthreads();
    if (r < N) {
        int wexcl = (wid == 0) ? 0 : ws[wid - 1];
        int run = tsum[blockIdx.x] + wexcl + (incl - tot);
        int out[NSUB];
        #pragma unroll
        for (int p = 0; p < NSUB; ++p) { out[p] = run; run += v[p]; }
        int4* dst = (int4*)(rs + (size_t)r * NSUB);
        dst[0] = make_int4(out[0], out[1], out[2], out[3]);
        dst[1] = make_int4(out[4], out[5], out[6], out[7]);
    }
}

__global__ void row_start_kernel(const int* __restrict__ rs,
                                 int* __restrict__ row_start,
                                 int N, int total_entries) {
    int r = blockIdx.x * blockDim.x + threadIdx.x;
    if (r > N) return;
    row_start[r] = (r == N) ? total_entries : rs[(size_t)r * NSUB];
}

// ---------------------------------------------------------------------------
// K3: fill unified adjacency (global neighbor id, raw softplus weight).
// ---------------------------------------------------------------------------
__global__ void fill_kernel(const float* __restrict__ logit,
                            const int* __restrict__ cu,
                            const int* __restrict__ ci,
                            const int* __restrict__ rs,
                            const int* __restrict__ pos_u,
                            const int* __restrict__ pos_i,
                            int2* __restrict__ adj,
                            int NU, int E) {
    int e = blockIdx.x * blockDim.x + threadIdx.x;
    if (e >= E) return;
    float x = logit[e];
    float w = fmaxf(x, 0.f) + log1pf(expf(-fabsf(x))) + EPSV;  // stable softplus
    int wb = __float_as_int(w);
    int su = e & 7;
    int si = (e >> 3) & 7;
    int u = cu[e];
    int gi = NU + ci[e];
    adj[rs[(size_t)u * NSUB + su]  + pos_u[e]] = make_int2(gi, wb);
    adj[rs[(size_t)gi * NSUB + si] + pos_i[e]] = make_int2(u,  wb);
}

// ---------------------------------------------------------------------------
// K4/K5: degree -> rsqrt, then scale adjacency to final norm.
// ---------------------------------------------------------------------------
__global__ void deg_kernel(const int2* __restrict__ adj,
                           const int* __restrict__ row_start,
                           float* __restrict__ rsq, int N) {
    int row  = blockIdx.x * (blockDim.x >> 6) + (threadIdx.x >> 6);
    int lane = threadIdx.x & 63;
    if (row >= N) return;
    int b = row_start[row], end = row_start[row + 1];
    float s = 0.f;
    for (int j = b + lane; j < end; j += 64) s += __int_as_float(adj[j].y);
    #pragma unroll
    for (int off = 1; off < 64; off <<= 1) s += __shfl_xor(s, off, 64);
    if (lane == 0) rsq[row] = rsqrtf(s + EPSV);
}

__global__ void scale_kernel(int2* __restrict__ adj,
                             const int* __restrict__ row_start,
                             const float* __restrict__ rsq, int N) {
    int row  = blockIdx.x * (blockDim.x >> 6) + (threadIdx.x >> 6);
    int lane = threadIdx.x & 63;
    if (row >= N) return;
    float rr = rsq[row];
    int b = row_start[row], end = row_start[row + 1];
    for (int j = b + lane; j < end; j += 64) {
        int2 v = adj[j];
        v.y = __float_as_int(__int_as_float(v.y) * rr * rsq[v.x]);
        adj[j] = v;
    }
}

// ---------------------------------------------------------------------------
// K6: init F0 = bf16(w + delta). 4 elems/thread, float4 in, ushort4 out.
// ---------------------------------------------------------------------------
__global__ void init_kernel(const float* __restrict__ user_w, const float* __restrict__ user_d,
                            const float* __restrict__ item_w, const float* __restrict__ item_d,
                            unsigned short* __restrict__ F0, int nu64, int total) {
    int idx = (blockIdx.x * blockDim.x + threadIdx.x) * 4;
    if (idx >= total) return;
    float4 w, d;
    if (idx < nu64) {
        w = *(const float4*)(user_w + idx);
        d = *(const float4*)(user_d + idx);
    } else {
        int j = idx - nu64;
        w = *(const float4*)(item_w + j);
        d = *(const float4*)(item_d + j);
    }
    ushort4 o;
    o.x = f2bf(w.x + d.x); o.y = f2bf(w.y + d.y);
    o.z = f2bf(w.z + d.z); o.w = f2bf(w.w + d.w);
    *(ushort4*)(F0 + idx) = o;
}

// ---------------------------------------------------------------------------
// K7: gather SpMM, bf16 src rows (128 B / row), f32 accumulate, bf16 dst.
// One wave per row, lane = feature dim. No accumulator traffic.
// ---------------------------------------------------------------------------
__global__ void __launch_bounds__(256)
gather_kernel(const int2* __restrict__ adj,
              const int* __restrict__ row_start,
              const unsigned short* __restrict__ src,
              unsigned short* __restrict__ dst,
              int N) {
    int row  = blockIdx.x * (blockDim.x >> 6) + (threadIdx.x >> 6);
    int lane = threadIdx.x & 63;
    if (row >= N) return;

    int k   = row_start[row];
    int end = row_start[row + 1];
    float a = 0.f;

    for (; k + 7 < end; k += 8) {
        int2 p0 = adj[k];     int2 p1 = adj[k + 1];
        int2 p2 = adj[k + 2]; int2 p3 = adj[k + 3];
        int2 p4 = adj[k + 4]; int2 p5 = adj[k + 5];
        int2 p6 = adj[k + 6]; int2 p7 = adj[k + 7];
        float s0 = bf2f(src[(size_t)p0.x * 64 + lane]);
        float s1 = bf2f(src[(size_t)p1.x * 64 + lane]);
        float s2 = bf2f(src[(size_t)p2.x * 64 + lane]);
        float s3 = bf2f(src[(size_t)p3.x * 64 + lane]);
        float s4 = bf2f(src[(size_t)p4.x * 64 + lane]);
        float s5 = bf2f(src[(size_t)p5.x * 64 + lane]);
        float s6 = bf2f(src[(size_t)p6.x * 64 + lane]);
        float s7 = bf2f(src[(size_t)p7.x * 64 + lane]);
        a += __int_as_float(p0.y) * s0;
        a += __int_as_float(p1.y) * s1;
        a += __int_as_float(p2.y) * s2;
        a += __int_as_float(p3.y) * s3;
        a += __int_as_float(p4.y) * s4;
        a += __int_as_float(p5.y) * s5;
        a += __int_as_float(p6.y) * s6;
        a += __int_as_float(p7.y) * s7;
    }
    for (; k + 3 < end; k += 4) {
        int2 p0 = adj[k];     int2 p1 = adj[k + 1];
        int2 p2 = adj[k + 2]; int2 p3 = adj[k + 3];
        float s0 = bf2f(src[(size_t)p0.x * 64 + lane]);
        float s1 = bf2f(src[(size_t)p1.x * 64 + lane]);
        float s2 = bf2f(src[(size_t)p2.x * 64 + lane]);
        float s3 = bf2f(src[(size_t)p3.x * 64 + lane]);
        a += __int_as_float(p0.y) * s0;
        a += __int_as_float(p1.y) * s1;
        a += __int_as_float(p2.y) * s2;
        a += __int_as_float(p3.y) * s3;
    }
    for (; k < end; ++k) {
        int2 p = adj[k];
        a += __int_as_float(p.y) * bf2f(src[(size_t)p.x * 64 + lane]);
    }

    dst[(size_t)row * 64 + lane] = f2bf(a);
}

// ---------------------------------------------------------------------------
// K8: epilogue — out = 0.25*((w+delta) + F1 + F2 + F3). Layer-0 term exact f32.
// ---------------------------------------------------------------------------
__global__ void finish_kernel(const float* __restrict__ user_w, const float* __restrict__ user_d,
                              const float* __restrict__ item_w, const float* __restrict__ item_d,
                              const unsigned short* __restrict__ F1,
                              const unsigned short* __restrict__ F2,
                              const unsigned short* __restrict__ F3,
                              float* __restrict__ out, int nu64, int total) {
    int idx = (blockIdx.x * blockDim.x + threadIdx.x) * 4;
    if (idx >= total) return;
    float4 w, d;
    if (idx < nu64) {
        w = *(const float4*)(user_w + idx);
        d = *(const float4*)(user_d + idx);
    } else {
        int j = idx - nu64;
        w = *(const float4*)(item_w + j);
        d = *(const float4*)(item_d + j);
    }
    ushort4 a = *(const ushort4*)(F1 + idx);
    ushort4 b = *(const ushort4*)(F2 + idx);
    ushort4 c = *(const ushort4*)(F3 + idx);
    float4 o;
    o.x = 0.25f * (w.x + d.x + bf2f(a.x) + bf2f(b.x) + bf2f(c.x));
    o.y = 0.25f * (w.y + d.y + bf2f(a.y) + bf2f(b.y) + bf2f(c.y));
    o.z = 0.25f * (w.z + d.z + bf2f(a.z) + bf2f(b.z) + bf2f(c.z));
    o.w = 0.25f * (w.w + d.w + bf2f(a.w) + bf2f(b.w) + bf2f(c.w));
    *(float4*)(out + idx) = o;
}

// ---------------------------------------------------------------------------
extern "C" void kernel_launch(void* const* d_in, const int* in_sizes, int n_in,
                              void* d_out, int out_size, void* d_ws, size_t ws_size,
                              hipStream_t stream) {
    const float* user_w = (const float*)d_in[0];
    const float* item_w = (const float*)d_in[1];
    const float* user_d = (const float*)d_in[2];
    const float* item_d = (const float*)d_in[3];
    const float* logit  = (const float*)d_in[4];
    const int*   cu     = (const int*)d_in[5];
    const int*   ci     = (const int*)d_in[6];

    const int NU = in_sizes[0] / 64;
    const int NI = in_sizes[1] / 64;
    const int E  = in_sizes[4];
    const int N  = NU + NI;
    const int NT = (N + ROWS_PER_TILE - 1) / ROWS_PER_TILE;  // 147 <= 256

    // ---- workspace carve-up (256 B aligned); cnt FIRST (single memset) ----
    char* ws = (char*)d_ws;
    size_t off = 0;
    auto carve = [&](size_t bytes) -> void* {
        void* p = ws + off;
        off = (off + bytes + 255) & ~(size_t)255;
        return p;
    };
    int*   cnt   = (int*)carve((size_t)NSUB * N * 4);   // zeroed each call
    size_t zero_bytes = off;
    int*   rs    = (int*)carve((size_t)NSUB * N * 4);
    int*   rstart= (int*)carve((size_t)(N + 1) * 4);
    float* rsq   = (float*)carve((size_t)N * 4);
    int*   tsum  = (int*)carve((size_t)256 * 4);
    int*   pos_u = (int*)carve((size_t)E * 4);
    int*   pos_i = (int*)carve((size_t)E * 4);
    int2*  adj   = (int2*)carve((size_t)2 * E * 8);
    unsigned short* F0 = (unsigned short*)carve((size_t)N * 64 * 2);
    unsigned short* F1 = (unsigned short*)carve((size_t)N * 64 * 2);
    unsigned short* F2 = (unsigned short*)carve((size_t)N * 64 * 2);
    unsigned short* F3 = (unsigned short*)carve((size_t)N * 64 * 2);
    (void)ws_size;

    float* out = (float*)d_out;
    hipMemsetAsync(cnt, 0, zero_bytes, stream);

    // ---- build phase ----
    {
        int eblocks = (E + 255) / 256;
        count_pos_kernel<<<eblocks, 256, 0, stream>>>(cu, ci, cnt, pos_u, pos_i,
                                                      NU, N, E);
        tile_sum_kernel<<<NT, ROWS_PER_TILE, 0, stream>>>(cnt, tsum, N);
        scan_tsum_kernel<<<1, 256, 0, stream>>>(tsum, NT);
        scan_tile_kernel<<<NT, ROWS_PER_TILE, 0, stream>>>(cnt, tsum, rs, N);
        row_start_kernel<<<(N + 256) / 256, 256, 0, stream>>>(rs, rstart, N, 2 * E);
        fill_kernel<<<eblocks, 256, 0, stream>>>(logit, cu, ci, rs, pos_u, pos_i,
                                                 adj, NU, E);
        int rblocks = (N + 3) / 4;
        deg_kernel<<<rblocks, 256, 0, stream>>>(adj, rstart, rsq, N);
        scale_kernel<<<rblocks, 256, 0, stream>>>(adj, rstart, rsq, N);
    }

    // ---- init F0 ----
    int total = N * 64;
    init_kernel<<<(total / 4 + 255) / 256, 256, 0, stream>>>(user_w, user_d,
                                                             item_w, item_d,
                                                             F0, NU * 64, total);

    // ---- 3 propagation layers ----
    int rblocks = (N + 3) / 4;
    gather_kernel<<<rblocks, 256, 0, stream>>>(adj, rstart, F0, F1, N);
    gather_kernel<<<rblocks, 256, 0, stream>>>(adj, rstart, F1, F2, N);
    gather_kernel<<<rblocks, 256, 0, stream>>>(adj, rstart, F2, F3, N);

    // ---- epilogue: out = 0.25*((w+delta) + F1 + F2 + F3) ----
    finish_kernel<<<(total / 4 + 255) / 256, 256, 0, stream>>>(user_w, user_d,
                                                               item_w, item_d,
                                                               F1, F2, F3,
                                                               out, NU * 64, total);
}